// Round 8
// baseline (145.974 us; speedup 1.0000x reference)
//
#include <hip/hip_runtime.h>
#include <stdint.h>

// SelfAttention: B=4, T=2048, EMB=1024, causal + key padding (last 256 keys)
#define TB 2048
#define DD 1024

typedef __bf16 bf16x8 __attribute__((ext_vector_type(8)));
typedef float  f32x16 __attribute__((ext_vector_type(16)));
typedef int    int4v  __attribute__((ext_vector_type(4)));
typedef unsigned u32;

__device__ __forceinline__ u32 pack2(float hi, float lo) {
  return (__float_as_uint(hi) & 0xffff0000u) | (__float_as_uint(lo) >> 16);
}
__device__ __forceinline__ bf16x8 pack8(const float f[8]) {
  int4v w;
  w.x = (int)pack2(f[1], f[0]);
  w.y = (int)pack2(f[3], f[2]);
  w.z = (int)pack2(f[5], f[4]);
  w.w = (int)pack2(f[7], f[6]);
  return __builtin_bit_cast(bf16x8, w);
}

// ===================== fused pre-pass: Q,K,V -> bf16 fragments =====================
// Q/K frag layout: [b][t32=T/32][ds=D/16][lane=64][8] bf16; Q scaled by 1/32.
// Vf layout: [b][dt=D/32][ks=T/16][lane=64][8] bf16 (transposed).
__global__ __launch_bounds__(256)
void conv_all(const float* __restrict__ Q, const float* __restrict__ K,
              const float* __restrict__ V,
              unsigned short* __restrict__ Qf, unsigned short* __restrict__ Kf,
              unsigned short* __restrict__ Vf) {
  __shared__ __align__(16) float t[64 * 260];
  if (blockIdx.x < 512) {
    const int isQ = blockIdx.x >> 8;
    const int bid = blockIdx.x & 255;
    const float* src0 = isQ ? Q : K;
    unsigned short* dst0 = isQ ? Qf : Kf;
    const float scl = isQ ? 0.03125f : 1.0f;
    const int b  = bid >> 6;
    const int kt = bid & 63;
    const int lt  = threadIdx.x & 63;
    const int row = lt & 31, hi = lt >> 5;
    const int wv  = threadIdx.x >> 6;
    const float* src = src0 + ((size_t)(b * TB + kt * 32 + row)) * DD + hi * 8;
    unsigned short* dst = dst0 + ((size_t)(b * 64 + kt) * 64) * 512 + lt * 8;
    #pragma unroll
    for (int i = 0; i < 16; ++i) {
      const int ds = wv + 4 * i;
      const float4 a = *(const float4*)(src + ds * 16);
      const float4 c = *(const float4*)(src + ds * 16 + 4);
      const float f[8] = {a.x*scl, a.y*scl, a.z*scl, a.w*scl,
                          c.x*scl, c.y*scl, c.z*scl, c.w*scl};
      *(int4v*)(dst + (size_t)ds * 512) = __builtin_bit_cast(int4v, pack8(f));
    }
  } else {
    const int bid = blockIdx.x - 512;
    const int b   = bid >> 7;
    const int kb  = (bid >> 2) & 31;
    const int db  = bid & 3;
    const int k0 = kb * 64, d0 = db * 256;
    {
      const int f = threadIdx.x & 63;
      const int r0 = threadIdx.x >> 6;
      #pragma unroll
      for (int i = 0; i < 16; ++i) {
        const int kloc = r0 + 4 * i;
        const float4 v4 = *(const float4*)(V + ((size_t)(b * TB + k0 + kloc)) * DD + d0 + f * 4);
        *(float4*)(t + kloc * 260 + f * 4) = v4;
      }
    }
    __syncthreads();
    const int lt  = threadIdx.x & 63;
    const int lo5 = lt & 31, hi = lt >> 5;
    const int kk  = threadIdx.x >> 6;
    #pragma unroll
    for (int dd = 0; dd < 8; ++dd) {
      float f[8];
      #pragma unroll
      for (int j = 0; j < 8; ++j)
        f[j] = t[(kk * 16 + hi * 8 + j) * 260 + dd * 32 + lo5];
      unsigned short* dst = Vf +
          (((size_t)(b * 32 + (d0 >> 5) + dd) * 128 + (k0 >> 4) + kk) * 64 + lt) * 8;
      *(int4v*)dst = __builtin_bit_cast(int4v, pack8(f));
    }
  }
}

// ===================== main kernel v7: QBLK=64, swapped QK, key-split ns ==========
// Block = (b, qt 0..31 [64 rows], split h). Tiles kt = h, h+ns, ... (256 keys each).
// QK: wave w owns keys [k0+32w,+32), both q-halves share each K fragment (1 K read).
// PV: wave w owns d slice [128w,+128); P per 128-key chunk (2 phases), V read once.
// Partials (bf16, unnormalized) -> OP[h]; (m,l) -> ML[h].
__global__ __launch_bounds__(512, 2)
void fa_fwd_f32_v7(const unsigned short* __restrict__ Qf, const int* __restrict__ AM,
                   const unsigned short* __restrict__ Kf, const unsigned short* __restrict__ Vf,
                   unsigned short* __restrict__ OP, float* __restrict__ ML, int ns)
{
  __shared__ __align__(16) unsigned short lds_Q[2 * 64 * 64 * 8];  // 131072 B [qh][ds][lane][8]
  __shared__ __align__(16) unsigned short lds_P[2 * 8 * 64 * 8];   // 16384 B [qh][kcl][lane][8]
  __shared__ float lds_red[8][64];                                 // 2048 B
  __shared__ unsigned char lds_nib[512];
  __shared__ int lds_tvi;

  const int tid  = threadIdx.x;
  const int w    = tid >> 6;
  const int lane = tid & 63;
  const int lo5  = lane & 31;
  const int hi   = lane >> 5;

  const int bid  = blockIdx.x;
  const int xcd  = bid & 7, slot = bid >> 3;
  const int b    = xcd >> 1, x = xcd & 1;
  int qt, h;
  if (ns == 4) { qt = 31 - (slot & 31); h = 2 * (slot >> 5) + x; }
  else         { qt = 31 - slot;        h = x; }
  const int q0 = qt << 6;

  // ---- pad-mask nibbles + per-256-tile validity ----
  if (tid == 0) lds_tvi = 0;
  __syncthreads();
  {
    const int4v mi = *(const int4v*)(AM + b * TB + 4 * tid);
    const unsigned char nib = (mi.x?1:0)|(mi.y?2:0)|(mi.z?4:0)|(mi.w?8:0);
    lds_nib[tid] = nib;
    if (nib) atomicOr(&lds_tvi, 1 << (tid >> 6));
  }
  __syncthreads();
  const int tvbits = lds_tvi;

  const int nkt = (qt >> 2) + 1;
  bool any = false;
  for (int kt = h; kt < nkt; kt += ns)
    if (tvbits & (1 << kt)) any = true;
  float* mlh = ML + h * 16384 + b * TB + q0;
  if (!any) {           // empty job: record (m,l)=(-inf,0), merge gives weight 0
    if (w == 0 && lane < 32) {
      mlh[lo5] = -1e30f; mlh[32 + lo5] = -1e30f;
      mlh[8192 + lo5] = 0.f; mlh[8192 + 32 + lo5] = 0.f;
    }
    return;
  }

  // ---- stage Q (both 32-row halves, frag order, contiguous copy) ----
  {
    const char* qsrc = (const char*)Qf + (size_t)(b * 64 + qt * 2) * 65536 + tid * 16;
    #pragma unroll
    for (int i = 0; i < 16; ++i)
      *(int4v*)((char*)lds_Q + tid * 16 + i * 8192) = *(const int4v*)(qsrc + (size_t)i * 8192);
  }
  __syncthreads();

  float mA = -1e30f, lA = 0.f, mB = -1e30f, lB = 0.f;
  f32x16 oA[4] = {f32x16{}, f32x16{}, f32x16{}, f32x16{}};
  f32x16 oB[4] = {f32x16{}, f32x16{}, f32x16{}, f32x16{}};

  const char* vbase = (const char*)Vf + (size_t)(b * 32 + 4 * w) * 131072 + lane * 16;
  const int qA = q0 + lo5, qB = qA + 32;
  const int dkt = qt >> 2;

  for (int kt = h; kt < nkt; kt += ns) {
    if (!(tvbits & (1 << kt))) continue;
    const int k0 = kt << 8;

    // ---- QK^T swapped, both halves share K fragment (2 chains) ----
    f32x16 sa{}, sb{};
    {
      const char* kp = (const char*)Kf + (size_t)(b * 64 + kt * 8 + w) * 65536 + lane * 16;
      const char* qa = (const char*)lds_Q + lane * 16;
      const char* qb = qa + 65536;
      __builtin_amdgcn_s_setprio(1);
      #pragma unroll 4
      for (int ds = 0; ds < 64; ++ds) {
        const bf16x8 kf = *(const bf16x8*)kp;
        sa = __builtin_amdgcn_mfma_f32_32x32x16_bf16(kf, *(const bf16x8*)qa, sa, 0, 0, 0);
        sb = __builtin_amdgcn_mfma_f32_32x32x16_bf16(kf, *(const bf16x8*)qb, sb, 0, 0, 0);
        kp += 1024; qa += 1024; qb += 1024;
      }
      __builtin_amdgcn_s_setprio(0);
    }

    // ---- mask (fast path off-diagonal) + per-lane max ----
    u32 mw;
    {
      const u32* nw = (const u32*)(lds_nib + 64 * kt + 8 * w);
      const u32 n0 = nw[0], n1 = nw[1];
      mw = (n0 & 0xFu) | ((n0 >> 4) & 0xF0u) | ((n0 >> 8) & 0xF00u) | ((n0 >> 12) & 0xF000u);
      mw |= ((n1 & 0xFu) | ((n1 >> 4) & 0xF0u) | ((n1 >> 8) & 0xF00u) | ((n1 >> 12) & 0xF000u)) << 16;
    }
    float mxA = -1e30f, mxB = -1e30f;
    if (kt != dkt && mw == 0xffffffffu) {
      #pragma unroll
      for (int r = 0; r < 16; ++r) { mxA = fmaxf(mxA, sa[r]); mxB = fmaxf(mxB, sb[r]); }
    } else {
      #pragma unroll
      for (int r = 0; r < 16; ++r) {
        const int kl = (r & 3) + 8 * (r >> 2) + 4 * hi;
        const int kg = k0 + 32 * w + kl;
        const bool pv = ((mw >> kl) & 1u) != 0u;
        sa[r] = (pv && kg <= qA) ? sa[r] : -1e30f;
        sb[r] = (pv && kg <= qB) ? sb[r] : -1e30f;
        mxA = fmaxf(mxA, sa[r]); mxB = fmaxf(mxB, sb[r]);
      }
    }
    mxA = fmaxf(mxA, __shfl_xor(mxA, 32, 64));
    mxB = fmaxf(mxB, __shfl_xor(mxB, 32, 64));
    if (lane < 32) { lds_red[w][lo5] = mxA; lds_red[w][32 + lo5] = mxB; }
    __syncthreads();                                   // BAR1

    float gA = mA, gB = mB;
    #pragma unroll
    for (int j = 0; j < 8; ++j) {
      gA = fmaxf(gA, lds_red[j][lo5]);
      gB = fmaxf(gB, lds_red[j][32 + lo5]);
    }
    const float scA = __expf(mA - gA), scB = __expf(mB - gB);
    mA = gA; mB = gB;
    const float pmA = fmaxf(gA, -1e28f), pmB = fmaxf(gB, -1e28f);
    float lsA = 0.f, lsB = 0.f;
    #pragma unroll
    for (int r = 0; r < 16; ++r) {
      sa[r] = __expf(sa[r] - pmA); lsA += sa[r];
      sb[r] = __expf(sb[r] - pmB); lsB += sb[r];
    }
    lsA += __shfl_xor(lsA, 32, 64);
    lsB += __shfl_xor(lsB, 32, 64);
    lA = lA * scA + lsA; lB = lB * scB + lsB;
    #pragma unroll
    for (int nb = 0; nb < 4; ++nb)
      #pragma unroll
      for (int r = 0; r < 16; ++r) { oA[nb][r] *= scA; oB[nb][r] *= scB; }

    // P^T frag write (both halves) for this wave's 32 keys; chunk-local slot 2*(w&3)+c
    #define WRITE_P()                                                            \
    {                                                                            \
      const int kcl0 = 2 * (w & 3);                                              \
      _Pragma("unroll")                                                          \
      for (int c = 0; c < 2; ++c) {                                              \
        const u32 a0 = pack2(sa[8*c+1], sa[8*c+0]);                              \
        const u32 a1 = pack2(sa[8*c+3], sa[8*c+2]);                              \
        const u32 a2 = pack2(sa[8*c+5], sa[8*c+4]);                              \
        const u32 a3 = pack2(sa[8*c+7], sa[8*c+6]);                              \
        const u32 xa0 = (u32)__shfl_xor((int)a0, 32, 64);                        \
        const u32 xa1 = (u32)__shfl_xor((int)a1, 32, 64);                        \
        const u32 xa2 = (u32)__shfl_xor((int)a2, 32, 64);                        \
        const u32 xa3 = (u32)__shfl_xor((int)a3, 32, 64);                        \
        int4v fA;                                                                \
        if (hi) { fA.x=(int)xa2; fA.y=(int)xa3; fA.z=(int)a2;  fA.w=(int)a3;  }  \
        else    { fA.x=(int)a0;  fA.y=(int)a1;  fA.z=(int)xa0; fA.w=(int)xa1; }  \
        *(int4v*)((char*)lds_P + ((kcl0 + c) * 64 + lane) * 16) = fA;            \
        const u32 b0 = pack2(sb[8*c+1], sb[8*c+0]);                              \
        const u32 b1 = pack2(sb[8*c+3], sb[8*c+2]);                              \
        const u32 b2 = pack2(sb[8*c+5], sb[8*c+4]);                              \
        const u32 b3 = pack2(sb[8*c+7], sb[8*c+6]);                              \
        const u32 xb0 = (u32)__shfl_xor((int)b0, 32, 64);                        \
        const u32 xb1 = (u32)__shfl_xor((int)b1, 32, 64);                        \
        const u32 xb2 = (u32)__shfl_xor((int)b2, 32, 64);                        \
        const u32 xb3 = (u32)__shfl_xor((int)b3, 32, 64);                        \
        int4v fB;                                                                \
        if (hi) { fB.x=(int)xb2; fB.y=(int)xb3; fB.z=(int)b2;  fB.w=(int)b3;  }  \
        else    { fB.x=(int)b0;  fB.y=(int)b1;  fB.z=(int)xb0; fB.w=(int)xb1; }  \
        *(int4v*)((char*)lds_P + 8192 + ((kcl0 + c) * 64 + lane) * 16) = fB;     \
      }                                                                          \
    }

    if (w < 4) WRITE_P();                              // keys [k0, k0+128)
    __syncthreads();                                   // BAR2: P chunk0 ready
    __builtin_amdgcn_s_setprio(1);
    #pragma unroll
    for (int kcl = 0; kcl < 8; ++kcl) {
      const bf16x8 pbA = *(const bf16x8*)((const char*)lds_P + (kcl * 64 + lane) * 16);
      const bf16x8 pbB = *(const bf16x8*)((const char*)lds_P + 8192 + (kcl * 64 + lane) * 16);
      const char* vp = vbase + (size_t)(kt * 16 + kcl) * 1024;
      #pragma unroll
      for (int nb = 0; nb < 4; ++nb) {
        const bf16x8 vf = *(const bf16x8*)(vp + (size_t)nb * 131072);
        oA[nb] = __builtin_amdgcn_mfma_f32_32x32x16_bf16(vf, pbA, oA[nb], 0, 0, 0);
        oB[nb] = __builtin_amdgcn_mfma_f32_32x32x16_bf16(vf, pbB, oB[nb], 0, 0, 0);
      }
    }
    __builtin_amdgcn_s_setprio(0);
    __syncthreads();                                   // BAR3: PV0 done
    if (w >= 4) WRITE_P();                             // keys [k0+128, k0+256)
    __syncthreads();                                   // BAR4: P chunk1 ready
    __builtin_amdgcn_s_setprio(1);
    #pragma unroll
    for (int kcl = 0; kcl < 8; ++kcl) {
      const bf16x8 pbA = *(const bf16x8*)((const char*)lds_P + (kcl * 64 + lane) * 16);
      const bf16x8 pbB = *(const bf16x8*)((const char*)lds_P + 8192 + (kcl * 64 + lane) * 16);
      const char* vp = vbase + (size_t)(kt * 16 + 8 + kcl) * 1024;
      #pragma unroll
      for (int nb = 0; nb < 4; ++nb) {
        const bf16x8 vf = *(const bf16x8*)(vp + (size_t)nb * 131072);
        oA[nb] = __builtin_amdgcn_mfma_f32_32x32x16_bf16(vf, pbA, oA[nb], 0, 0, 0);
        oB[nb] = __builtin_amdgcn_mfma_f32_32x32x16_bf16(vf, pbB, oB[nb], 0, 0, 0);
      }
    }
    __builtin_amdgcn_s_setprio(0);
    #undef WRITE_P
  }

  // ---- epilogue: lane-32 exchange -> 16B q-major bf16 stores (both halves) ----
  {
    unsigned short* obA = OP + (size_t)h * 8388608 +
                          ((size_t)(b * TB + q0 + lo5)) * DD + 128 * w;
    unsigned short* obB = obA + (size_t)32 * DD;
    #pragma unroll
    for (int nb = 0; nb < 4; ++nb) {
      #pragma unroll
      for (int m2 = 0; m2 < 4; ++m2) {
        const u32 e0 = pack2(oA[nb][4*m2+1], oA[nb][4*m2+0]);
        const u32 e1 = pack2(oA[nb][4*m2+3], oA[nb][4*m2+2]);
        const u32 y0 = (u32)__shfl_xor((int)e0, 32, 64);
        const u32 y1 = (u32)__shfl_xor((int)e1, 32, 64);
        const u32 g0 = pack2(oB[nb][4*m2+1], oB[nb][4*m2+0]);
        const u32 g1 = pack2(oB[nb][4*m2+3], oB[nb][4*m2+2]);
        const u32 z0 = (u32)__shfl_xor((int)g0, 32, 64);
        const u32 z1 = (u32)__shfl_xor((int)g1, 32, 64);
        if (hi == (nb >> 1)) {
          int4v fA, fB;
          if (hi) { fA.x=(int)y0; fA.y=(int)y1; fA.z=(int)e0; fA.w=(int)e1;
                    fB.x=(int)z0; fB.y=(int)z1; fB.z=(int)g0; fB.w=(int)g1; }
          else    { fA.x=(int)e0; fA.y=(int)e1; fA.z=(int)y0; fA.w=(int)y1;
                    fB.x=(int)g0; fB.y=(int)g1; fB.z=(int)z0; fB.w=(int)z1; }
          *(int4v*)(obA + 32 * nb + 8 * m2) = fA;
          *(int4v*)(obB + 32 * nb + 8 * m2) = fB;
        }
      }
    }
  }
  if (lane < 32) { lds_red[w][lo5] = lA; lds_red[w][32 + lo5] = lB; }
  __syncthreads();
  if (w == 0 && lane < 32) {
    float la = 0.f, lb = 0.f;
    #pragma unroll
    for (int j = 0; j < 8; ++j) { la += lds_red[j][lo5]; lb += lds_red[j][32 + lo5]; }
    mlh[lo5] = mA;  mlh[32 + lo5] = mB;
    mlh[8192 + lo5] = la;  mlh[8192 + 32 + lo5] = lb;
  }
}

// ===================== merge: O = sum_s e_s*OP_s / sum_s e_s*l_s ====================
template<int NS>
__global__ __launch_bounds__(256)
void merge_ns(float* __restrict__ O, const unsigned short* __restrict__ OP,
              const float* __restrict__ ML) {
  const int idx = blockIdx.x * 256 + threadIdx.x;   // 16 elems per thread
  const int row = idx >> 6;
  float mx[NS], lx[NS], fx[NS];
  float mm = -1e30f;
  #pragma unroll
  for (int s = 0; s < NS; ++s) {
    mx[s] = ML[s * 16384 + row];
    lx[s] = ML[s * 16384 + 8192 + row];
    mm = fmaxf(mm, mx[s]);
  }
  float den = 0.f;
  #pragma unroll
  for (int s = 0; s < NS; ++s) { fx[s] = __expf(mx[s] - mm); den += fx[s] * lx[s]; }
  const float inv = 1.0f / den;
  float out[16];
  #pragma unroll
  for (int i = 0; i < 16; ++i) out[i] = 0.f;
  #pragma unroll
  for (int s = 0; s < NS; ++s) {
    const float f = fx[s] * inv;
    const uint4* p = (const uint4*)(OP + (size_t)s * 8388608 + (size_t)idx * 16);
    #pragma unroll
    for (int g = 0; g < 2; ++g) {
      const uint4 u = p[g];
      const u32 wv[4] = {u.x, u.y, u.z, u.w};
      #pragma unroll
      for (int i = 0; i < 4; ++i) {
        out[8*g+2*i]   += f * __uint_as_float(wv[i] << 16);
        out[8*g+2*i+1] += f * __uint_as_float(wv[i] & 0xffff0000u);
      }
    }
  }
  float4* od = (float4*)(O + (size_t)idx * 16);
  od[0] = make_float4(out[0],  out[1],  out[2],  out[3]);
  od[1] = make_float4(out[4],  out[5],  out[6],  out[7]);
  od[2] = make_float4(out[8],  out[9],  out[10], out[11]);
  od[3] = make_float4(out[12], out[13], out[14], out[15]);
}

// ===================== fallback (v1, known good, no workspace) ======================
__global__ __launch_bounds__(512, 2)
void fa_fwd_f32_v1(const float* __restrict__ Q, const float* __restrict__ K,
                   const float* __restrict__ V, const int* __restrict__ AM,
                   float* __restrict__ O)
{
  __shared__ __align__(16) float lds_part[8][32 * 68];
  __shared__ __align__(16) unsigned short lds_Pf[32][72];
  __shared__ float lds_m[32], lds_l[32], lds_scale[32];
  __shared__ unsigned lds_mask32[TB / 4];
  __shared__ int lds_tv[32];

  const int tid  = threadIdx.x;
  const int w    = tid >> 6;
  const int lane = tid & 63;
  const int lo5  = lane & 31;
  const int hi   = lane >> 5;

  const int bid  = blockIdx.x;
  const int xcd  = bid & 7;
  const int slot = bid >> 3;
  const int b    = xcd >> 1;
  const int half = xcd & 1;
  const int qt   = half ? (16 + slot) : (slot < 16 ? slot : 32 + slot);
  const int q0   = qt << 5;

  const int4v mi = *(const int4v*)(AM + b * TB + 4 * tid);
  const unsigned mw = (mi.x ? 1u : 0u) | (mi.y ? 0x100u : 0u) |
                      (mi.z ? 0x10000u : 0u) | (mi.w ? 0x1000000u : 0u);
  lds_mask32[tid] = mw;
  if (tid < 32) { lds_tv[tid] = 0; lds_m[tid] = -1e30f; lds_l[tid] = 0.0f; }
  __syncthreads();
  if (mw) lds_tv[tid >> 4] = 1;

  bf16x8 qf[8];
  {
    const float* qrow = Q + ((size_t)b * TB + q0 + lo5) * DD + w * 128 + hi * 8;
    #pragma unroll
    for (int kk = 0; kk < 8; ++kk) {
      const float4 a = *(const float4*)(qrow + kk * 16);
      const float4 c = *(const float4*)(qrow + kk * 16 + 4);
      const float f[8] = {a.x * 0.03125f, a.y * 0.03125f, a.z * 0.03125f, a.w * 0.03125f,
                          c.x * 0.03125f, c.y * 0.03125f, c.z * 0.03125f, c.w * 0.03125f};
      qf[kk] = pack8(f);
    }
  }

  f32x16 oacc[4] = {f32x16{}, f32x16{}, f32x16{}, f32x16{}};
  const float* kbat = K + (size_t)b * TB * DD + w * 128 + hi * 8;
  const float* vbat = V + (size_t)b * TB * DD + w * 128;
  __syncthreads();

  const int nkt = (qt >> 1) + 1;
  for (int kt = 0; kt < nkt; ++kt) {
    if (!lds_tv[kt]) continue;
    const int k0 = kt << 6;
    f32x16 s0{}, s1{};
    const float* kb0 = kbat + (size_t)(k0 + lo5) * DD;
    #pragma unroll
    for (int kk = 0; kk < 8; ++kk) {
      const float4 a0 = *(const float4*)(kb0 + kk * 16);
      const float4 a1 = *(const float4*)(kb0 + kk * 16 + 4);
      const float f0[8] = {a0.x, a0.y, a0.z, a0.w, a1.x, a1.y, a1.z, a1.w};
      s0 = __builtin_amdgcn_mfma_f32_32x32x16_bf16(qf[kk], pack8(f0), s0, 0, 0, 0);
      const float4 c0 = *(const float4*)(kb0 + (size_t)32 * DD + kk * 16);
      const float4 c1 = *(const float4*)(kb0 + (size_t)32 * DD + kk * 16 + 4);
      const float f1[8] = {c0.x, c0.y, c0.z, c0.w, c1.x, c1.y, c1.z, c1.w};
      s1 = __builtin_amdgcn_mfma_f32_32x32x16_bf16(qf[kk], pack8(f1), s1, 0, 0, 0);
    }
    {
      float* wp = lds_part[w];
      const int pos = lo5 + (hi << 5);
      #pragma unroll
      for (int r = 0; r < 16; ++r) {
        wp[r * 68 + pos]        = s0[r];
        wp[(16 + r) * 68 + pos] = s1[r];
      }
    }
    __syncthreads();
    {
      const int r = tid >> 4, g = tid & 15;
      const int regp  = (r & 3) | (((r >> 3) & 3) << 2);
      const int plane = ((g >> 3) << 4) + regp;
      const int pos   = ((4 * g) & 31) + (((r >> 2) & 1) << 5);
      float s[4] = {0.f, 0.f, 0.f, 0.f};
      #pragma unroll
      for (int ww = 0; ww < 8; ++ww) {
        const float4 v4 = *(const float4*)&lds_part[ww][plane * 68 + pos];
        s[0] += v4.x; s[1] += v4.y; s[2] += v4.z; s[3] += v4.w;
      }
      const unsigned mv = lds_mask32[(k0 >> 2) + g];
      const int qq = q0 + r;
      #pragma unroll
      for (int i = 0; i < 4; ++i) {
        const int kg = k0 + 4 * g + i;
        const bool ok = (((mv >> (8 * i)) & 0xffu) != 0u) && (kg <= qq);
        if (!ok) s[i] = -1e30f;
      }
      float mx = fmaxf(fmaxf(s[0], s[1]), fmaxf(s[2], s[3]));
      #pragma unroll
      for (int d = 1; d < 16; d <<= 1) mx = fmaxf(mx, __shfl_xor(mx, d, 64));
      const float mold = lds_m[r];
      const float mnew = fmaxf(mold, mx);
      float p[4], lsv = 0.f;
      #pragma unroll
      for (int i = 0; i < 4; ++i) { p[i] = __expf(s[i] - mnew); lsv += p[i]; }
      #pragma unroll
      for (int d = 1; d < 16; d <<= 1) lsv += __shfl_xor(lsv, d, 64);
      const float resc = __expf(mold - mnew);
      if (g == 0) {
        lds_m[r]     = mnew;
        lds_l[r]     = lds_l[r] * resc + lsv;
        lds_scale[r] = resc;
      }
      unsigned* pp = (unsigned*)&lds_Pf[r][4 * g];
      pp[0] = pack2(p[1], p[0]);
      pp[1] = pack2(p[3], p[2]);
    }
    __syncthreads();
    {
      float scv[16];
      #pragma unroll
      for (int reg = 0; reg < 16; ++reg)
        scv[reg] = lds_scale[(reg & 3) + ((reg >> 2) << 3) + (hi << 2)];
      #pragma unroll
      for (int nb = 0; nb < 4; ++nb) {
        #pragma unroll
        for (int reg = 0; reg < 16; ++reg) oacc[nb][reg] *= scv[reg];
      }
      bf16x8 pf[4];
      #pragma unroll
      for (int kc = 0; kc < 4; ++kc)
        pf[kc] = __builtin_bit_cast(bf16x8, *(const int4v*)&lds_Pf[lo5][kc * 16 + hi * 8]);
      const float* vbp = vbat + (size_t)k0 * DD + lo5;
      #pragma unroll
      for (int kc = 0; kc < 4; ++kc) {
        const float* vr = vbp + (size_t)(kc * 16 + hi * 8) * DD;
        float fv[4][8];
        #pragma unroll
        for (int j = 0; j < 8; ++j) {
          const float* vrj = vr + (size_t)j * DD;
          #pragma unroll
          for (int nb = 0; nb < 4; ++nb) fv[nb][j] = vrj[nb * 32];
        }
        #pragma unroll
        for (int nb = 0; nb < 4; ++nb)
          oacc[nb] = __builtin_amdgcn_mfma_f32_32x32x16_bf16(pf[kc], pack8(fv[nb]), oacc[nb], 0, 0, 0);
      }
    }
    __syncthreads();
  }

  float il[16];
  #pragma unroll
  for (int reg = 0; reg < 16; ++reg)
    il[reg] = 1.0f / lds_l[(reg & 3) + ((reg >> 2) << 3) + (hi << 2)];
  float* ob = O + ((size_t)b * TB + q0) * DD + w * 128;
  #pragma unroll
  for (int nb = 0; nb < 4; ++nb) {
    #pragma unroll
    for (int reg = 0; reg < 16; ++reg) {
      const int row = (reg & 3) + ((reg >> 2) << 3) + (hi << 2);
      ob[(size_t)row * DD + nb * 32 + lo5] = oacc[nb][reg] * il[reg];
    }
  }
}

extern "C" void kernel_launch(void* const* d_in, const int* in_sizes, int n_in,
                              void* d_out, int out_size, void* d_ws, size_t ws_size,
                              hipStream_t stream) {
  const float* Q  = (const float*)d_in[0];
  const float* K  = (const float*)d_in[1];
  const float* V  = (const float*)d_in[2];
  const int*   AM = (const int*)d_in[3];
  float* O = (float*)d_out;
  (void)in_sizes; (void)n_in; (void)out_size;

  const size_t SZ = 16777216;                       // Kf/Vf/Qf/partial each
  const size_t need4 = 7 * SZ + 4 * 65536;          // 3 frag + 4 partials + ML
  const size_t need2 = 5 * SZ + 2 * 65536;          // 3 frag + 2 partials + ML
  unsigned short* Kf = (unsigned short*)d_ws;
  unsigned short* Vf = (unsigned short*)((char*)d_ws + SZ);
  unsigned short* Qf = (unsigned short*)((char*)d_ws + 2 * SZ);
  unsigned short* OP = (unsigned short*)((char*)d_ws + 3 * SZ);

  if (ws_size >= need4) {
    float* ML = (float*)((char*)d_ws + 7 * SZ);
    hipLaunchKernelGGL(conv_all, dim3(1024), dim3(256), 0, stream, Q, K, V, Qf, Kf, Vf);
    hipLaunchKernelGGL(fa_fwd_f32_v7, dim3(512), dim3(512), 0, stream,
                       Qf, AM, Kf, Vf, OP, ML, 4);
    hipLaunchKernelGGL(merge_ns<4>, dim3(2048), dim3(256), 0, stream, O, OP, ML);
  } else if (ws_size >= need2) {
    float* ML = (float*)((char*)d_ws + 5 * SZ);
    hipLaunchKernelGGL(conv_all, dim3(1024), dim3(256), 0, stream, Q, K, V, Qf, Kf, Vf);
    hipLaunchKernelGGL(fa_fwd_f32_v7, dim3(256), dim3(512), 0, stream,
                       Qf, AM, Kf, Vf, OP, ML, 2);
    hipLaunchKernelGGL(merge_ns<2>, dim3(2048), dim3(256), 0, stream, O, OP, ML);
  } else {
    hipLaunchKernelGGL(fa_fwd_f32_v1, dim3(256), dim3(512), 0, stream, Q, K, V, AM, O);
  }
}